// Round 8
// baseline (4495.802 us; speedup 1.0000x reference)
//
#include <hip/hip_runtime.h>

typedef unsigned short u16;
typedef short short8 __attribute__((ext_vector_type(8)));
typedef float f32x4 __attribute__((ext_vector_type(4)));
typedef unsigned int u32x4 __attribute__((ext_vector_type(4)));
typedef unsigned int u32x2 __attribute__((ext_vector_type(2)));

#define Bsz 32
#define Tsz 512
#define Dsz 1024
#define Usz 1024
#define Gsz 4096   // 4*U

#define SENTINEL 0x7FC0u   // bf16 NaN; |h|<1 strictly (|c|<=n by induction, o<1), never legit

// ---- bf16 helpers (manual RNE) ----
static __device__ __forceinline__ u16 f2bf(float f) {
    unsigned int u = __float_as_uint(f);
    unsigned int lsb = (u >> 16) & 1u;
    u += 0x7fffu + lsb;
    return (u16)(u >> 16);
}
static __device__ __forceinline__ float bf2f(u16 b) {
    return __uint_as_float(((unsigned int)b) << 16);
}
// per-lane: any bf16 in this 16B chunk has exponent all-ones (sentinel / unwritten)?
static __device__ __forceinline__ unsigned badchunk(short8 v) {
    u32x4 xw = __builtin_bit_cast(u32x4, v);
    unsigned bad = 0;
#pragma unroll
    for (int k = 0; k < 4; ++k) {
        unsigned m = xw[k] & 0x7F807F80u;
        bad |= (unsigned)((m >> 16) == 0x7F80u);
        bad |= (unsigned)((m & 0xFFFFu) == 0x7F80u);
    }
    return bad;
}

// =====================================================================
// Pack kernels: MFMA-fragment-ordered bf16 buffers.
// A-frag (16x16x32): lane L holds A[m = mt*16 + (L&15)][k = kb*32 + (L>>4)*8 + j]
// B-frag:            lane L holds B[k = kb*32 + (L>>4)*8 + j][n = nt*16 + (L&15)]
// Flat: buf[((tile*32 + kb)*64 + L)*8 + j] -> lane-contiguous 16B chunks.
// =====================================================================

__global__ __launch_bounds__(256) void pack_a(const float* __restrict__ x, u16* __restrict__ Af) {
    size_t tid = (size_t)blockIdx.x * 256 + threadIdx.x;
    int L = (int)(tid & 63);
    size_t mtkb = tid >> 6;
    int kb = (int)(mtkb & 31);
    int mt = (int)(mtkb >> 5);
    int m  = mt * 16 + (L & 15);
    int d0 = kb * 32 + (L >> 4) * 8;
    const float* src = x + (size_t)m * Dsz + d0;
    short8 v;
#pragma unroll
    for (int j = 0; j < 8; ++j) v[j] = (short)f2bf(src[j]);
    *(short8*)(Af + tid * 8) = v;
}

__global__ __launch_bounds__(256) void pack_b(const float* __restrict__ W, u16* __restrict__ Bf) {
    size_t tid = (size_t)blockIdx.x * 256 + threadIdx.x;
    int L = (int)(tid & 63);
    size_t ntkb = tid >> 6;
    int kb = (int)(ntkb & 31);
    int nt = (int)(ntkb >> 5);
    int n  = nt * 16 + (L & 15);
    int k0 = kb * 32 + (L >> 4) * 8;
    short8 v;
#pragma unroll
    for (int j = 0; j < 8; ++j) v[j] = (short)f2bf(W[(size_t)(k0 + j) * Gsz + n]);
    *(short8*)(Bf + tid * 8) = v;
}

// R -> Rp gate-interleaved: tile=blk (0..255), col c=gate*4+du -> g=gate*1024+blk*4+du.
// Also initializes the h ring buffers (ws is poisoned 0xAA before every call!):
//   hbf layout: [G(2)][ring p(4)][row(16)][u(1024)] bf16 (each buffer 16384 u16).
//   Ring p=3 holds h_{-1}=0 (read at t=0); p=0,1,2 start as SENTINEL.
__global__ __launch_bounds__(256) void pack_r(const float* __restrict__ R, u16* __restrict__ Rp,
                                              u16* __restrict__ hbf) {
    size_t tid = (size_t)blockIdx.x * 256 + threadIdx.x;
    if (tid < 131072) {
        int p = (int)((tid >> 14) & 3);
        hbf[tid] = (p == 3) ? (u16)0 : (u16)SENTINEL;
    }
    int L = (int)(tid & 63);
    size_t bkkb = tid >> 6;
    int kb  = (int)(bkkb & 31);
    int blk = (int)(bkkb >> 5);
    int c = L & 15;
    int gate = c >> 2, du = c & 3;
    int g = gate * 1024 + blk * 4 + du;
    int k0 = kb * 32 + (L >> 4) * 8;
    short8 v;
#pragma unroll
    for (int j = 0; j < 8; ++j) v[j] = (short)f2bf(R[(size_t)(k0 + j) * Gsz + g]);
    *(short8*)(Rp + tid * 8) = v;
}

// =====================================================================
// GEMM1: x_proj = X @ W; 128x128 tile, 4 waves. Epilogue writes the
// scan-friendly layout: [t][b][tile(256)][du(4)][gate(4)] so each scan
// gate-lane reads exactly one float4/u32x2 per (t,b).
// =====================================================================
__global__ __launch_bounds__(256) void gemm1(const u16* __restrict__ Af, const u16* __restrict__ Bf,
                                             float* __restrict__ xpf, u16* __restrict__ xph, int xp32) {
    __shared__ u16 smem[16 * 512];
    int bm = blockIdx.x >> 5;
    int bn = blockIdx.x & 31;
    int tid = threadIdx.x;
    int w = tid >> 6, ln = tid & 63;
    int mw = w & 1, nw = w >> 1;

    f32x4 acc[4][4];
#pragma unroll
    for (int i = 0; i < 4; ++i)
#pragma unroll
        for (int j = 0; j < 4; ++j) acc[i][j] = (f32x4){0.f, 0.f, 0.f, 0.f};

    for (int kb = 0; kb < 32; ++kb) {
        short8 tmp[4];
#pragma unroll
        for (int c2 = 0; c2 < 4; ++c2) {
            int chunk = w * 4 + c2;
            const u16* src = (chunk < 8)
                ? Af + (((size_t)(bm * 8 + chunk) * 32 + kb) * 64 + ln) * 8
                : Bf + (((size_t)(bn * 8 + (chunk - 8)) * 32 + kb) * 64 + ln) * 8;
            tmp[c2] = *(const short8*)src;
        }
#pragma unroll
        for (int c2 = 0; c2 < 4; ++c2) {
            int chunk = w * 4 + c2;
            *(short8*)(smem + chunk * 512 + ln * 8) = tmp[c2];
        }
        __syncthreads();
        short8 av[4], bv[4];
#pragma unroll
        for (int i = 0; i < 4; ++i) av[i] = *(const short8*)(smem + (mw * 4 + i) * 512 + ln * 8);
#pragma unroll
        for (int j = 0; j < 4; ++j) bv[j] = *(const short8*)(smem + (8 + nw * 4 + j) * 512 + ln * 8);
#pragma unroll
        for (int i = 0; i < 4; ++i)
#pragma unroll
            for (int j = 0; j < 4; ++j)
                acc[i][j] = __builtin_amdgcn_mfma_f32_16x16x32_bf16(av[i], bv[j], acc[i][j], 0, 0, 0);
        __syncthreads();
    }

    int quad = ln >> 4, c15 = ln & 15;
#pragma unroll
    for (int i = 0; i < 4; ++i) {
        int mt_g = bm * 8 + mw * 4 + i;
#pragma unroll
        for (int j = 0; j < 4; ++j) {
            int g = (bn * 8 + nw * 4 + j) * 16 + c15;
            int p = ((g & 1023) >> 2) * 16 + (g & 3) * 4 + (g >> 10);
#pragma unroll
            for (int r = 0; r < 4; ++r) {
                int row = mt_g * 16 + quad * 4 + r;
                int bb = row >> 9, tt = row & 511;
                size_t o = ((size_t)tt * Bsz + bb) * Gsz + p;
                if (xp32) xpf[o] = acc[i][j][r];
                else      xph[o] = f2bf(acc[i][j][r]);
            }
        }
    }
}

// =====================================================================
// Scan (r8): 256 blocks x 640 threads (10 waves), ONE barrier per step.
//   waves 0-3 : MFMA G0 (K-slice (w&3)*256)
//   waves 4-7 : MFMA G1 (same K-slices; R shared in LDS)
//   wave  8/9 : gate wave G0/G1
// Per step t:
//   MFMA: sentinel-validated bypass-load of h_G(t-1) from ring slot
//         (t+3)&3 (chunk-wise retry: only dirty 16B chunks reloaded,
//         s_sleep 2 backoff) -> MFMA -> partial[G][t&1][wg] -> BARRIER
//   gate: after the SAME barrier: reduce 4 partials -> proj transpose ->
//         vmcnt(0) [drains x_proj prefetch AND last step's h/sentinel/out
//         stores -- ack deferred off the critical tail] -> gates ->
//         out + h(t)->ring[t&3] + SENTINEL->ring[(t+2)&3] (no drain!) ->
//         x_proj prefetch (t+1) -> next barrier.
// Ring safety (drain deferred one step, re-proved):
//  - WAW: sentinel(t, slot (t+2)&3) drained by gate's vmcnt(0) in step
//    t+1, before h(t+2) hits that slot in step t+2.
//  - stale-read: consumer validates h(t+1) only after producer's step-
//    t+1 vmcnt(0) drained sentinel(t) (h(t+1) issued after that drain),
//    so a later read of slot (t+2)&3 sees sentinel-or-h(t+2), never
//    h(t-2).
//  - partial parity-2: MFMA iter t+2 overwrites partial[t&1] after
//    barrier(t+1); gate's reads of partial[t&1] precede its arrival at
//    barrier(t+1).
// =====================================================================
__global__ __launch_bounds__(640) void scan_all(const float* __restrict__ xpf,
                                                const u16* __restrict__ xph, int xp32,
                                                const u16* __restrict__ Rp,
                                                const float* __restrict__ bias,
                                                u16* __restrict__ hbf, float* __restrict__ out) {
    __shared__ u16 lds_r[16384];             // 32KB: this block's Rp slice (16 cols x K=1024)
    __shared__ f32x4 partial[2][2][4][64];   // 16KB: [G][par][wg][lane]
    __shared__ float proj[2][16][17];        // 2.2KB, per-group

    int tid = threadIdx.x;
    int blk = blockIdx.x;
    int w = tid >> 6, ln = tid & 63, quad = ln >> 4, c15 = ln & 15;
    int bq = ln >> 2, du = ln & 3;           // gate-wave lane decomposition
    int u_g = blk * 4 + du;

    // ---- stage Rp slice into LDS (fragment order preserved) ----
    for (int c = tid; c < 2048; c += 640)
        *(short8*)(lds_r + (size_t)c * 8) = *(const short8*)(Rp + (size_t)blk * 16384 + (size_t)c * 8);

    float bi0 = 0.f, bi1 = 0.f, bi2 = 0.f, bi3 = 0.f;
    float cs = 0.f, ns = 0.f, ms = 0.f;      // gate state (one G per gate wave)
    f32x4 xr4 = (f32x4){0.f, 0.f, 0.f, 0.f};
    u32x2 xr2 = (u32x2){0u, 0u};

    if (w >= 8) {                            // gate waves: bias + t=0 x_proj
        int Gg = w - 8;
        bi0 = bias[u_g]; bi1 = bias[1024 + u_g]; bi2 = bias[2048 + u_g]; bi3 = bias[3072 + u_g];
        size_t o0 = (size_t)(Gg * 16 + bq) * Gsz + blk * 16 + du * 4;   // t=0
        if (xp32) xr4 = *(const f32x4*)(xpf + o0);
        else      xr2 = *(const u32x2*)(xph + o0);
    }
    __syncthreads();                         // lds_r ready (h ring inited by pack_r)

    int G  = (w < 8) ? (w >> 2) : (w - 8);
    int wg = w & 3;

    for (int t = 0; t < Tsz; ++t) {
        if (w < 8) {
            // ---- sentinel-validated bypass-load of h_{t-1}, chunk-wise retry ----
            const u16* hbase = hbf + ((size_t)(G * 4 + ((t + 3) & 3)) << 14)
                                   + (size_t)c15 * 1024 + wg * 256 + quad * 8;
            short8 av[8];
#define LDH(i, OFF) asm volatile("global_load_dwordx4 %0, %1, off offset:" OFF " sc0 sc1" \
                                 : "=v"(av[i]) : "v"(hbase))
            LDH(0, "0");   LDH(1, "64");  LDH(2, "128"); LDH(3, "192");
            LDH(4, "256"); LDH(5, "320"); LDH(6, "384"); LDH(7, "448");
            asm volatile("s_waitcnt vmcnt(0)" ::: "memory");
            __builtin_amdgcn_sched_barrier(0);
            unsigned dirty = 0;
#pragma unroll
            for (int i = 0; i < 8; ++i)
                if (__any((int)badchunk(av[i]))) dirty |= (1u << i);
            while (dirty) {
                asm volatile("s_sleep 2" ::: "memory");
                if (dirty & 0x01u) LDH(0, "0");
                if (dirty & 0x02u) LDH(1, "64");
                if (dirty & 0x04u) LDH(2, "128");
                if (dirty & 0x08u) LDH(3, "192");
                if (dirty & 0x10u) LDH(4, "256");
                if (dirty & 0x20u) LDH(5, "320");
                if (dirty & 0x40u) LDH(6, "384");
                if (dirty & 0x80u) LDH(7, "448");
                asm volatile("s_waitcnt vmcnt(0)" ::: "memory");
                __builtin_amdgcn_sched_barrier(0);
#pragma unroll
                for (int i = 0; i < 8; ++i)
                    if ((dirty & (1u << i)) && !__any((int)badchunk(av[i]))) dirty &= ~(1u << i);
            }
#undef LDH
            __builtin_amdgcn_sched_barrier(0);

            // ---- MFMA: K=256 per wave, 2 independent chains ----
            f32x4 a0 = (f32x4){0.f, 0.f, 0.f, 0.f};
            f32x4 a1 = (f32x4){0.f, 0.f, 0.f, 0.f};
#pragma unroll
            for (int kk = 0; kk < 8; kk += 2) {
                short8 b0 = *(const short8*)(lds_r + ((wg * 8 + kk) * 64 + ln) * 8);
                short8 b1 = *(const short8*)(lds_r + ((wg * 8 + kk + 1) * 64 + ln) * 8);
                a0 = __builtin_amdgcn_mfma_f32_16x16x32_bf16(av[kk], b0, a0, 0, 0, 0);
                a1 = __builtin_amdgcn_mfma_f32_16x16x32_bf16(av[kk + 1], b1, a1, 0, 0, 0);
            }
            partial[G][t & 1][wg][ln] = a0 + a1;
        }
        __syncthreads();                     // the ONLY barrier per step
        if (w >= 8) {
            // ---- reduce 4 K-slices, transpose via proj (within-wave) ----
            int par = t & 1;
            f32x4 s = partial[G][par][0][ln];
            s += partial[G][par][1][ln];
            s += partial[G][par][2][ln];
            s += partial[G][par][3][ln];
#pragma unroll
            for (int r = 0; r < 4; ++r) proj[G][quad * 4 + r][c15] = s[r];
            asm volatile("s_waitcnt lgkmcnt(0)" ::: "memory");
            __builtin_amdgcn_sched_barrier(0);

            // drains x_proj prefetch AND last step's h/sentinel/out stores
            asm volatile("s_waitcnt vmcnt(0)" : "+v"(xr4), "+v"(xr2) :: "memory");
            __builtin_amdgcn_sched_barrier(0);
            float xv0, xv1, xv2, xv3;
            if (xp32) { xv0 = xr4[0]; xv1 = xr4[1]; xv2 = xr4[2]; xv3 = xr4[3]; }
            else {
                xv0 = bf2f((u16)(xr2[0] & 0xffffu)); xv1 = bf2f((u16)(xr2[0] >> 16));
                xv2 = bf2f((u16)(xr2[1] & 0xffffu)); xv3 = bf2f((u16)(xr2[1] >> 16));
            }

            float ip  = proj[G][bq][du]      + xv0 + bi0;
            float fp_ = proj[G][bq][4 + du]  + xv1 + bi1;
            float op_ = proj[G][bq][8 + du]  + xv2 + bi2;
            float zp  = proj[G][bq][12 + du] + xv3 + bi3;
            float sf = 1.f / (1.f + __expf(-fp_));
            float lf = __logf(sf + 1e-8f);
            float mn = fmaxf(ms + lf, ip);
            float it = __expf(ip - mn);
            float ft = __expf(ms + lf - mn);
            float ot = 1.f / (1.f + __expf(-op_));
            float zt = tanhf(zp);
            cs = ft * cs + it * zt;
            ns = ft * ns + it;
            ms = mn;
            float h = ot * (cs / (ns + 1e-8f));
            out[(size_t)(G * 16 + bq) * (Tsz * Usz) + (size_t)t * Usz + u_g] = h;

            // ---- h -> ring[t&3], SENTINEL -> ring[(t+2)&3]; NO drain here ----
            size_t chunk = (size_t)bq * 1024 + u_g;
            u16* hp = hbf + ((size_t)(G * 4 + (t & 3)) << 14) + chunk;
            u16* sp = hbf + ((size_t)(G * 4 + ((t + 2) & 3)) << 14) + chunk;
            unsigned hv = (unsigned)f2bf(h);
            unsigned sv = SENTINEL;
            asm volatile("global_store_short %0, %1, off sc0 sc1" :: "v"(hp), "v"(hv) : "memory");
            asm volatile("global_store_short %0, %1, off sc0 sc1" :: "v"(sp), "v"(sv) : "memory");

            // ---- issue x_proj prefetch for t+1 (left in flight) ----
            int tn = (t + 1 < Tsz) ? t + 1 : t;
            size_t o = ((size_t)tn * Bsz + (G * 16 + bq)) * Gsz + blk * 16 + du * 4;
            if (xp32) {
                const float* p = xpf + o;
                asm volatile("global_load_dwordx4 %0, %1, off" : "=v"(xr4) : "v"(p));
            } else {
                const u16* p = xph + o;
                asm volatile("global_load_dwordx2 %0, %1, off" : "=v"(xr2) : "v"(p));
            }
        }
    }
}

// =====================================================================
extern "C" void kernel_launch(void* const* d_in, const int* in_sizes, int n_in,
                              void* d_out, int out_size, void* d_ws, size_t ws_size,
                              hipStream_t stream) {
    const float* x    = (const float*)d_in[0];
    const float* W    = (const float*)d_in[1];
    const float* R    = (const float*)d_in[2];
    const float* bias = (const float*)d_in[3];
    float* out = (float*)d_out;

    char* ws = (char*)d_ws;
    size_t off = 0;
    u16* Af = (u16*)(ws + off); off += (size_t)16384 * 1024 * 2;  // 32MB
    u16* Bf = (u16*)(ws + off); off += (size_t)1024 * 4096 * 2;   // 8MB
    u16* Rp = (u16*)(ws + off); off += (size_t)1024 * 4096 * 2;   // 8MB
    u16* hbf = (u16*)(ws + off); off += (size_t)1 << 20;          // 1MB (256KB used: 2G x 4-ring x 32KB)
    off += 4096;                                                  // (legacy slot, unused)
    size_t xp_need32 = (size_t)16384 * 4096 * 4;                  // 256MB
    int xp32 = (ws_size >= off + xp_need32) ? 1 : 0;
    float* xpf = (float*)(ws + off);
    u16*   xph = (u16*)(ws + off);

    pack_a<<<dim3(8192), dim3(256), 0, stream>>>(x, Af);
    pack_b<<<dim3(2048), dim3(256), 0, stream>>>(W, Bf);
    pack_r<<<dim3(2048), dim3(256), 0, stream>>>(R, Rp, hbf);
    gemm1<<<dim3(4096), dim3(256), 0, stream>>>(Af, Bf, xpf, xph, xp32);

    void* args[] = { (void*)&xpf, (void*)&xph, (void*)&xp32, (void*)&Rp,
                     (void*)&bias, (void*)&hbf, (void*)&out };
    hipLaunchCooperativeKernel((const void*)scan_all, dim3(256), dim3(640), args, 0, stream);
}